// Round 6
// baseline (547.439 us; speedup 1.0000x reference)
//
#include <hip/hip_runtime.h>
#include <cstdint>
#include <cmath>

// Problem dims
#define B_   128
#define N_   196
#define D_   768
#define H_   3072
#define R_   384
#define TOK  (B_*N_)      // 25088

typedef int i32x4 __attribute__((ext_vector_type(4)));

// async global->LDS, 16B per lane; LDS dest = wave-uniform base + lane*16
#define GLDS16(g, l) __builtin_amdgcn_global_load_lds( \
    (const __attribute__((address_space(1))) void*)(g), \
    (__attribute__((address_space(3))) void*)(l), 16, 0, 0)

// s_waitcnt imm (gfx9): vmcnt[3:0], expcnt[6:4]=7, lgkmcnt[11:8]=15
#define WAITV4() __builtin_amdgcn_s_waitcnt(0xF74)   // vmcnt(4)
#define WAITV0() __builtin_amdgcn_s_waitcnt(0xF70)   // vmcnt(0)
#define WAITLGKM0() __asm__ volatile("s_waitcnt lgkmcnt(0)" ::: "memory")
#define BARRIER() do { __asm__ volatile("" ::: "memory"); \
                       __builtin_amdgcn_s_barrier(); \
                       __asm__ volatile("" ::: "memory"); } while (0)

// ---------------- workspace layout (bytes) ----------------
#define OFF_AMAX   0L
#define OFF_LUT    512L
#define OFF_QVEC   1024L
#define OFF_WQA    (32L*1024)
#define OFF_W1VT   (128L*1024)
#define OFF_W1U    (512L*1024)
#define OFF_W2VT   (2L*1024*1024)
#define OFF_W2U    (3328L*1024)
#define OFF_X1Q    (4L*1024*1024)
#define OFF_A4     (24L*1024*1024)
#define OFF_A7     (34L*1024*1024)
#define OFF_A0T    (44L*1024*1024)
#define OFF_A2     (68L*1024*1024)
#define OFF_A6     (44L*1024*1024)

__device__ __forceinline__ float rclipf(float v) {
  return fminf(fmaxf(rintf(v), -128.f), 127.f);
}

// ---------------- absmax over 9 weight tensors ----------------
__global__ void absmax_k(const float* p0, const float* p1, const float* p2,
                         const float* p3, const float* p4, const float* p5,
                         const float* p6, const float* p7, const float* p8,
                         float* amax) {
  int tsel = blockIdx.y;
  const float* src; int n;
  switch (tsel) {
    case 0: src = p0; n = 768;     break;
    case 1: src = p1; n = N_*N_;   break;
    case 2: src = p2; n = 768;     break;
    case 3: src = p3; n = 768;     break;
    case 4: src = p4; n = R_*D_;   break;
    case 5: src = p5; n = H_*R_;   break;
    case 6: src = p6; n = R_*H_;   break;
    case 7: src = p7; n = D_*R_;   break;
    default: src = p8; n = 768;    break;
  }
  float m = 0.f;
  for (int i = blockIdx.x*blockDim.x + threadIdx.x; i < n; i += gridDim.x*blockDim.x)
    m = fmaxf(m, fabsf(src[i]));
  #pragma unroll
  for (int off = 32; off > 0; off >>= 1)
    m = fmaxf(m, __shfl_down(m, off));
  if ((threadIdx.x & 63) == 0)
    atomicMax((int*)(amax + tsel), __float_as_int(m));
}

// ---------------- precompute epilogue vectors + GELU LUT ----------------
__global__ void prep_vec_k(const float* n1a, const float* n1b, const float* g1,
                           const float* n2a, const float* n2b, const float* g2,
                           const float* amax, const float* actS, float* dst,
                           int8_t* lut) {
  int i = threadIdx.x;  // 768
  float s0 = actS[0], s1 = actS[1], s2 = actS[2], s3 = actS[3];
  float s8 = actS[8], s9 = actS[9];
  float sw;
  sw = amax[0]/127.f + 1e-8f; float qn1a = sw * rclipf(n1a[i]/sw);
  dst[i]        = qn1a / s0;
  dst[768+i]    = n1b[i] / s0;
  sw = amax[2]/127.f + 1e-8f; float qg1 = sw * rclipf(g1[i]/sw);
  dst[1536+i]   = (s1 * qg1) / s8;
  sw = amax[3]/127.f + 1e-8f; float qn2a = sw * rclipf(n2a[i]/sw);
  dst[2304+i]   = (s8 * qn2a) / s2;
  dst[3072+i]   = n2b[i] / s2;
  sw = amax[8]/127.f + 1e-8f; float qg2 = sw * rclipf(g2[i]/sw);
  dst[3840+i]   = (s3 * qg2) / s9;
  if (i < 256) {
    float s5 = actS[5], s6 = actS[6];
    float v5 = s5 * (float)(i - 128);
    float g  = 0.5f * v5 * (1.f + erff(v5 * 0.70710678118654752f));
    lut[i] = (int8_t)(int)rclipf(g / s6);
  }
}

// ---------------- quantize all 5 matmul weights ----------------
__global__ void quant_all_k(const float* w1vt, const float* w1u, const float* w2vt,
                            const float* w2u, const float* attw, const float* amax,
                            int8_t* W1VT, int8_t* W1U, int8_t* W2VT, int8_t* W2U,
                            int8_t* WQA) {
  int sel = blockIdx.y;
  const float* src; int8_t* dst; int n; float am;
  switch (sel) {
    case 0: src = w1vt; dst = W1VT; n = R_*D_;  am = amax[4]; break;
    case 1: src = w1u;  dst = W1U;  n = H_*R_;  am = amax[5]; break;
    case 2: src = w2vt; dst = W2VT; n = R_*H_;  am = amax[6]; break;
    case 3: src = w2u;  dst = W2U;  n = D_*R_;  am = amax[7]; break;
    default: src = attw; dst = WQA; n = 65536;  am = amax[1]; break;
  }
  float s = am / 127.f + 1e-8f;
  if (sel < 4) {
    for (int i = blockIdx.x*blockDim.x + threadIdx.x; i < n; i += gridDim.x*blockDim.x)
      dst[i] = (int8_t)(int)rclipf(src[i] / s);
  } else {
    for (int i = blockIdx.x*blockDim.x + threadIdx.x; i < n; i += gridDim.x*blockDim.x) {
      int m = i >> 8, nn = i & 255;
      int8_t q = 0;
      if (m < N_ && nn < N_) q = (int8_t)(int)rclipf(attw[m*N_ + nn] / s);
      dst[i] = q;
    }
  }
}

// ---------------- stage A: norm1 affine + act-quant -> A0T[b][d][n256] ----------------
__global__ void stageA_k(const float* __restrict__ x, const float* __restrict__ n1as,
                         const float* __restrict__ n1bs, int8_t* __restrict__ A0T) {
  __shared__ int8_t ldsT[64*68];
  const int dt = blockIdx.x;
  const int nt = blockIdx.y;
  const int b  = blockIdx.z;
  const int d0 = dt*64, n0 = nt*64;
  const int tid = threadIdx.x;
  const int dc = tid & 63, nr4 = tid >> 6;
  const float qa = n1as[d0 + dc];
  const float bb = n1bs[d0 + dc];
  #pragma unroll 4
  for (int it = 0; it < 16; ++it) {
    int nl = nr4 + it*4;
    int n = n0 + nl;
    int8_t q = 0;
    if (n < N_) {
      float v = fmaf(x[((long)b*N_ + n)*D_ + d0 + dc], qa, bb);
      q = (int8_t)(int)rclipf(v);
    }
    ldsT[dc*68 + nl] = q;
  }
  __syncthreads();
  const int k = tid & 15, dr = tid >> 4;
  #pragma unroll
  for (int it = 0; it < 4; ++it) {
    int d = dr + it*16;
    uint32_t v = *(const uint32_t*)(&ldsT[d*68 + k*4]);
    *(uint32_t*)(&A0T[(long)b*(D_*256) + (long)(d0+d)*256 + n0 + k*4]) = v;
  }
}

// ---------------- shared param struct ----------------
struct GemmParams {
  const int8_t* A;
  const int8_t* W;
  int K, MT, NT;
  long batchStrideA;
  const float* actS;
  const float* amax;
  int amaxIdx, sInIdx, sOutIdx, sOut2Idx;
  const float* bias;
  int8_t* out8;
  int ldOut;
  const float* xorg;     // EPI0
  const float* g1s;
  const float* a2s8;
  const float* b2s;
  int8_t* X1q;
  int8_t* A2;
  const float* g2s9;     // EPI3
  const int8_t* X1qIn;
  float* outF;
  const int8_t* lutG;    // EPI2
};

// ---------------- attn GEMM (round-0 verified, EPI0) ----------------
template<int EPI>
__launch_bounds__(256, 4)
__global__ void gemm_i8(GemmParams p) {
  __shared__ __align__(16) int8_t lsA[2][128][64];
  __shared__ __align__(16) int8_t lsB[2][128][64];
  const int K  = p.K;
  const int bx = blockIdx.x;
  const int mt = bx % p.MT;
  const int nt = bx / p.MT;
  const int t    = threadIdx.x;
  const int wid  = t >> 6;
  const int lane = t & 63;
  const int wm = wid & 1, wn = wid >> 1;
  const int quad = lane >> 4, l15 = lane & 15;

  const int8_t* Abase = p.A + (long)blockIdx.y * p.batchStrideA + (long)mt*128*K;
  const int8_t* Wbase = p.W + (long)nt*128*K;

  const int8_t* Ab = Abase + (long)(t >> 2)*K + (t & 3)*16;
  const int8_t* Bb = Wbase + (long)(t >> 2)*K + (t & 3)*16;
  const long half = 64L * K;

  auto issue = [&](int kt) {
    const int buf = kt & 1;
    const long k = (long)kt << 6;
    GLDS16(Ab + k,        &lsA[buf][0][0]  + t*16);
    GLDS16(Ab + half + k, &lsA[buf][64][0] + t*16);
    GLDS16(Bb + k,        &lsB[buf][0][0]  + t*16);
    GLDS16(Bb + half + k, &lsB[buf][64][0] + t*16);
  };

  const i32x4 zero = {0, 0, 0, 0};
  i32x4 acc[4][4];
  #pragma unroll
  for (int i = 0; i < 4; ++i)
    #pragma unroll
    for (int j = 0; j < 4; ++j) acc[i][j] = zero;

  const int KT = K >> 6;
  issue(0);
  for (int kt = 0; kt < KT; ++kt) {
    const int cur = kt & 1;
    if (kt + 1 < KT) { issue(kt + 1); WAITV4(); }
    else             { WAITV0(); }
    BARRIER();
    i32x4 af[4], bf[4];
    #pragma unroll
    for (int i = 0; i < 4; ++i)
      af[i] = *(const i32x4*)(&lsA[cur][wm*64 + i*16 + l15][quad*16]);
    #pragma unroll
    for (int j = 0; j < 4; ++j)
      bf[j] = *(const i32x4*)(&lsB[cur][wn*64 + j*16 + l15][quad*16]);
    #pragma unroll
    for (int i = 0; i < 4; ++i)
      #pragma unroll
      for (int j = 0; j < 4; ++j)
        acc[i][j] = __builtin_amdgcn_mfma_i32_16x16x64_i8(af[i], bf[j], acc[i][j], 0, 0, 0);
    BARRIER();
  }

  const float sW  = p.amax[p.amaxIdx] / 127.f + 1e-8f;
  const float sAB = p.actS[p.sInIdx] * sW;
  const int i0 = mt*128 + wm*64;
  const int j0 = nt*128 + wn*64;

  #pragma unroll
  for (int ii = 0; ii < 4; ++ii) {
    const int i = i0 + ii*16 + quad*4;   // d (0..767)
    const float c1     = sAB / p.actS[1];
    const float inv_s8 = 1.f / p.actS[8];
    const float4 g1s4 = *(const float4*)(p.g1s + i);
    const float4 a2s4 = *(const float4*)(p.a2s8 + i);
    const float4 b2s4 = *(const float4*)(p.b2s + i);
    #pragma unroll
    for (int jj = 0; jj < 4; ++jj) {
      const int j = j0 + jj*16 + l15;    // m patch
      if (j < N_) {
        const float c2 = p.bias[j] / p.actS[1];
        const long tok = (long)blockIdx.y * N_ + j;
        const float4 xo = *(const float4*)(p.xorg + tok*D_ + i);
        uint32_t pk8 = 0, pk2 = 0;
        #pragma unroll
        for (int r = 0; r < 4; ++r) {
          float accf = (float)acc[ii][jj][r];
          float q1 = rclipf(fmaf(accf, c1, c2));
          float q8 = rclipf(fmaf(q1, ((const float*)&g1s4)[r],
                                 ((const float*)&xo)[r] * inv_s8));
          float q2 = rclipf(fmaf(q8, ((const float*)&a2s4)[r],
                                 ((const float*)&b2s4)[r]));
          pk8 |= ((uint32_t)(uint8_t)(int8_t)(int)q8) << (8*r);
          pk2 |= ((uint32_t)(uint8_t)(int8_t)(int)q2) << (8*r);
        }
        *(uint32_t*)(p.X1q + tok*D_ + i) = pk8;
        *(uint32_t*)(p.A2  + tok*D_ + i) = pk2;
      }
    }
  }
}

// ============ fc1u_areg: A-in-VGPR (W1U rows) + B-via-LDS pipeline ============
// Block: 512 thr / 8 waves. BM = 512 feat (wave w owns rows f0+w*64..+64,
// RESIDENT in 96 VGPR: af[6 kt][4 fr]); BN = 64 tokens shared block-wide;
// K = 384. B staged in PAIRS of kt (8KB) into 3 one-shot 8KB buffers,
// counted vmcnt, 3 barriers total in the K-loop. Per kt per wave: 4 bf
// ds_reads + 16 reg-fed MFMA (LDS traffic ~58% of matrix time vs ~100% in
// all prior variants; af ds_reads and their lgkm dep chains eliminated).
// Epilogue: GELU LUT (bank-replicated, +128 folded into bias) -> block-wide
// LDS bounce [64 tok][512+16] -> fully-coalesced 512B-per-row dwordx4 stores.
__launch_bounds__(512, 2)
__global__ void fc1u_areg(GemmParams p) {
  __shared__ __align__(16) int8_t lsB[3*8192];     // 3 pair-bufs [2][64 tok][64]
  __shared__ __align__(16) int8_t scrA6[64*528];   // bounce [64 tok][512+16]
  __shared__ uint32_t lutR[64*32];                 // bank-replicated GELU LUT

  const int t    = threadIdx.x;
  const int wid  = t >> 6;
  const int lane = t & 63;
  const int quad = lane >> 4, l15 = lane & 15, l31 = lane & 31;

  if (t < 64) {
    const uint8_t* lg = (const uint8_t*)p.lutG + t*4;
    uint32_t v = (uint32_t)lg[0] | ((uint32_t)lg[1] << 8) |
                 ((uint32_t)lg[2] << 16) | ((uint32_t)lg[3] << 24);
    #pragma unroll
    for (int c = 0; c < 32; ++c) lutR[t*32 + c] = v;
  }
  __syncthreads();

  // bijective XCD swizzle (grid 2352 = 8*294)
  int bx = blockIdx.x;
  { const int c = gridDim.x >> 3; bx = (bx & 7)*c + (bx >> 3); }
  const int mt = bx % 6;            // feature block of 512
  const int nt = bx / 6;            // token block of 64
  const long tk0 = (long)nt * 64;
  const int f0 = mt*512 + wid*64;   // this wave's resident rows

  // ---- A-resident: af[6 kt][4 fr], 96 VGPR ----
  i32x4 af[6][4];
  {
    const int8_t* Ab = p.A + ((long)f0 + l15)*R_ + quad*16;
    #pragma unroll
    for (int i = 0; i < 4; ++i)
      #pragma unroll
      for (int kt = 0; kt < 6; ++kt)
        af[kt][i] = *(const i32x4*)(Ab + (long)i*16*R_ + kt*64);
  }

  // ---- B staging (both-sides swizzle, r3-verified): pair pr covers kt 2pr..2pr+1
  // thread t: kt2 = t>>8, tok = (t>>2)&63, chunk = t&3 (src col pre-XOR'd)
  const int swz = ((t & 3) ^ ((t >> 3) & 3)) * 16;
  const int8_t* Bb = p.W + (tk0 + ((t >> 2) & 63))*R_ + (t >> 8)*64 + swz;
  auto stage = [&](int buf, int pr) {
    GLDS16(Bb + pr*128, lsB + buf*8192 + t*16);
  };
  stage(0, 0);
  stage(1, 1);
  __builtin_amdgcn_s_waitcnt(0xF71);   // vmcnt(1): A-regs + pair0 landed; pair1 in flight
  BARRIER();

  const int sq = (quad ^ ((l15 >> 1) & 3)) * 16;
  const i32x4 zero = {0, 0, 0, 0};
  i32x4 acc[4][4];
  #pragma unroll
  for (int i = 0; i < 4; ++i)
    #pragma unroll
    for (int j = 0; j < 4; ++j) acc[i][j] = zero;

  #pragma unroll
  for (int pr = 0; pr < 3; ++pr) {
    if (pr == 0) stage(2, 2);
    #pragma unroll
    for (int ktl = 0; ktl < 2; ++ktl) {
      const int kt = pr*2 + ktl;
      i32x4 bf[4];
      #pragma unroll
      for (int j = 0; j < 4; ++j)
        bf[j] = *(const i32x4*)(lsB + pr*8192 + ktl*4096 + (j*16 + l15)*64 + sq);
      #pragma unroll
      for (int i = 0; i < 4; ++i)
        #pragma unroll
        for (int j = 0; j < 4; ++j)
          acc[i][j] = __builtin_amdgcn_mfma_i32_16x16x64_i8(af[kt][i], bf[j], acc[i][j], 0, 0, 0);
    }
    if (pr == 0)      { __builtin_amdgcn_s_waitcnt(0xF71); BARRIER(); }  // pair1 landed
    else if (pr == 1) { WAITV0(); BARRIER(); }                           // pair2 landed
  }

  // ---- epilogue: GELU quant -> bounce -> coalesced stores ----
  // C/D layout: col = l15 (token), row = quad*4 + r (feature)
  const float sW = p.amax[5] / 127.f + 1e-8f;
  const float s5 = p.actS[5];
  const float c1 = (p.actS[4] * sW) / s5;
  #pragma unroll
  for (int i = 0; i < 4; ++i) {
    const int f = f0 + i*16 + quad*4;
    const float4 b4 = *(const float4*)(p.bias + f);
    float c2[4];
    #pragma unroll
    for (int r = 0; r < 4; ++r) c2[r] = ((const float*)&b4)[r] / s5 + 128.f;  // fold +128
    #pragma unroll
    for (int j = 0; j < 4; ++j) {
      const int row = j*16 + l15;
      uint32_t pk = 0;
      #pragma unroll
      for (int r = 0; r < 4; ++r) {
        float q = fminf(fmaxf(rintf(fmaf((float)acc[i][j][r], c1, c2[r])), 0.f), 255.f);
        int q5i = (int)q;
        uint32_t v = lutR[(q5i >> 2)*32 + l31];
        pk |= ((v >> ((q5i & 3)*8)) & 0xffu) << (8*r);
      }
      *(uint32_t*)(scrA6 + row*528 + wid*64 + i*16 + quad*4) = pk;
    }
  }
  WAITLGKM0();
  BARRIER();
  // flush: 64 rows x 512B; 2048 dwordx4 chunks over 512 threads x 4 iters
  #pragma unroll
  for (int e = 0; e < 4; ++e) {
    const int row = e*16 + (t >> 5);
    const int cc  = t & 31;
    i32x4 v = *(const i32x4*)(scrA6 + row*528 + cc*16);
    *(i32x4*)(p.out8 + (tk0 + row)*(long)H_ + mt*512 + cc*16) = v;
  }
}

// ============ gemm_wlds: weight-resident-in-LDS i8 GEMM (K<=384) ============
template<int EPI, int WM, int WN, int NFR, int KT, int NB>
__launch_bounds__(512, 2)
__global__ void gemm_wlds(GemmParams p) {
  constexpr int MFR = 16 / WM;
  constexpr int BN  = WN * NFR * 16;
  constexpr int K   = KT * 64;
  constexpr int ABYTES = 256 * K;
  constexpr int NA  = ABYTES / (512*16);
  constexpr int SRB = ((EPI == 3) ? 128 : MFR*16) + 16;
  static_assert(ABYTES + 3*BN*64 + (EPI==2 ? 8192 : 16) <= 160*1024, "LDS");
  static_assert(8 * 64 * SRB <= ABYTES, "scratch");
  __shared__ __align__(16) int8_t lsMem[ABYTES + 3*BN*64];
  __shared__ uint32_t lutR[(EPI == 2) ? 64*32 : 4];

  const int t    = threadIdx.x;
  const int wid  = t >> 6;
  const int lane = t & 63;
  const int wm = wid % WM, wn = wid / WM;
  const int quad = lane >> 4, l15 = lane & 15, l31 = lane & 31;

  if constexpr (EPI == 2) {
    if (t < 64) {
      const uint8_t* lg = (const uint8_t*)p.lutG + t*4;
      uint32_t v = (uint32_t)lg[0] | ((uint32_t)lg[1] << 8) |
                   ((uint32_t)lg[2] << 16) | ((uint32_t)lg[3] << 24);
      #pragma unroll
      for (int c = 0; c < 32; ++c) lutR[t*32 + c] = v;
    }
    __syncthreads();
  }

  int bx = blockIdx.x;
  { const int nwg = gridDim.x;
    if ((nwg & 7) == 0) { const int c = nwg >> 3; bx = (bx & 7)*c + (bx >> 3); } }
  const int mt = bx % p.MT;
  const int nt = bx / p.MT;

  {
    const int8_t* Abase = p.A + (long)mt*256*K;
    #pragma unroll
    for (int ld = 0; ld < NA; ++ld) {
      const int L = ld*512 + t;
      const int r = L & 255, s = L >> 8;
      GLDS16(Abase + (long)r*K + s*16, lsMem + ld*8192 + t*16);
    }
  }
  const int swz = ((t & 3) ^ ((t >> 3) & 3)) * 16;
  const int8_t* Bb = p.W + ((long)nt*BN + (t >> 2))*K + swz;
  auto issueB = [&](int buf, int kt) {
    const long kOff = (long)kt * 64;
    GLDS16(Bb + kOff, lsMem + ABYTES + buf*(BN*64) + t*16);
    if constexpr (NB == 2)
      GLDS16(Bb + 128L*K + kOff, lsMem + ABYTES + buf*(BN*64) + 8192 + t*16);
  };
  issueB(0, 0);
  issueB(1, 1);
  __builtin_amdgcn_s_waitcnt(0xF70 | NB);
  BARRIER();

  const int aBase = quad*4096 + (wm*(MFR*16) + l15)*16;
  const int sq = (quad ^ ((l15 >> 1) & 3)) * 16;

  const i32x4 zero = {0, 0, 0, 0};
  i32x4 acc[MFR][NFR];
  #pragma unroll
  for (int i = 0; i < MFR; ++i)
    #pragma unroll
    for (int j = 0; j < NFR; ++j) acc[i][j] = zero;

  int bufR = 0, bufW = 2;
  #pragma unroll 1
  for (int kt = 0; kt < KT; ++kt) {
    if (kt + 2 < KT) issueB(bufW, kt + 2);
    i32x4 af[MFR], bf[NFR];
    #pragma unroll
    for (int i = 0; i < MFR; ++i)
      af[i] = *(const i32x4*)(lsMem + aBase + kt*16384 + i*256);
    #pragma unroll
    for (int j = 0; j < NFR; ++j)
      bf[j] = *(const i32x4*)(lsMem + ABYTES +
                              (bufR*BN + wn*(NFR*16) + j*16 + l15)*64 + sq);
    __builtin_amdgcn_s_setprio(1);
    #pragma unroll
    for (int i = 0; i < MFR; ++i)
      #pragma unroll
      for (int j = 0; j < NFR; ++j)
        acc[i][j] = __builtin_amdgcn_mfma_i32_16x16x64_i8(af[i], bf[j], acc[i][j], 0, 0, 0);
    __builtin_amdgcn_s_setprio(0);
    if (kt + 2 < KT)      __builtin_amdgcn_s_waitcnt(0xF70 | NB);
    else if (kt + 1 < KT) WAITV0();
    if (kt + 1 < KT) BARRIER();
    bufR = (bufR == 2) ? 0 : bufR + 1;
    bufW = (bufW == 2) ? 0 : bufW + 1;
  }
  BARRIER();

  const float sW  = p.amax[p.amaxIdx] / 127.f + 1e-8f;
  const float sAB = p.actS[p.sInIdx] * sW;
  const int i0 = mt*256 + wm*(MFR*16);
  const int j0 = nt*BN + wn*(NFR*16);
  int8_t* scr = lsMem + wid * (64 * SRB);

  if constexpr (EPI == 2) {
    const float sO = p.actS[p.sOutIdx];
    const float c1 = sAB / sO;
    #pragma unroll
    for (int ii = 0; ii < MFR; ++ii) {
      const int i = i0 + ii*16 + quad*4;
      const float4 b4 = *(const float4*)(p.bias + i);
      float c2[4];
      #pragma unroll
      for (int r = 0; r < 4; ++r) c2[r] = ((const float*)&b4)[r] / sO;
      #pragma unroll
      for (int jj = 0; jj < NFR; ++jj) {
        uint32_t pk = 0;
        #pragma unroll
        for (int r = 0; r < 4; ++r) {
          int q5 = (int)rclipf(fmaf((float)acc[ii][jj][r], c1, c2[r])) + 128;
          uint32_t v = lutR[(q5 >> 2)*32 + l31];
          pk |= ((v >> ((q5 & 3)*8)) & 0xffu) << (8*r);
        }
        const int row = jj*16 + l15;
        *(uint32_t*)(scr + row*SRB + ii*16 + quad*4) = pk;
      }
    }
    WAITLGKM0();
    constexpr int CH = MFR;
    #pragma unroll
    for (int e = 0; e < CH; ++e) {
      const int c = e*64 + lane;
      const int row = c / CH, cc = c % CH;
      i32x4 v = *(const i32x4*)(scr + row*SRB + cc*16);
      *(i32x4*)(p.out8 + (long)(j0 + row)*p.ldOut + i0 + cc*16) = v;
    }
  } else {  // EPI == 3
    const float s3v = p.actS[3], s9v = p.actS[9];
    const float c1  = sAB / s3v;
    const float c89 = p.actS[8] / s9v;
    #pragma unroll
    for (int pp = 0; pp < MFR/2; ++pp) {
      #pragma unroll
      for (int iu = 0; iu < 2; ++iu) {
        const int ii = pp*2 + iu;
        const int i = i0 + ii*16 + quad*4;
        const float4 b4 = *(const float4*)(p.bias + i);
        const float4 g4 = *(const float4*)(p.g2s9 + i);
        float c2[4];
        #pragma unroll
        for (int r = 0; r < 4; ++r) c2[r] = ((const float*)&b4)[r] / s3v;
        #pragma unroll
        for (int jj = 0; jj < NFR; ++jj) {
          const int j = j0 + jj*16 + l15;
          const uint32_t pk8 = *(const uint32_t*)(p.X1qIn + (long)j*D_ + i);
          float4 o;
          #pragma unroll
          for (int r = 0; r < 4; ++r) {
            float q3 = rclipf(fmaf((float)acc[ii][jj][r], c1, c2[r]));
            float q8 = (float)(int8_t)(uint8_t)(pk8 >> (8*r));
            float q9 = rclipf(fmaf(q3, ((const float*)&g4)[r], q8 * c89));
            ((float*)&o)[r] = s9v * q9;
          }
          const int row = jj*16 + l15;
          *(float4*)(scr + row*SRB + iu*64 + quad*16) = o;
        }
      }
      WAITLGKM0();
      #pragma unroll
      for (int e = 0; e < 8; ++e) {
        const int c = e*64 + lane;
        const int row = c >> 3, cc = c & 7;
        float4 v = *(const float4*)(scr + row*SRB + cc*16);
        *(float4*)(p.outF + (long)(j0 + row)*D_ + i0 + pp*32 + cc*4) = v;
      }
      WAITLGKM0();
    }
  }
}

// ============ gemm_s1: lean 128x128 single-phase counted-vmcnt i8 GEMM ============
template<int EPI, int KT>
__launch_bounds__(512, 4)
__global__ void gemm_s1(GemmParams p) {
  constexpr int K = KT * 64;
  __shared__ __align__(16) int8_t lsMem[6*8192];
  const int t    = threadIdx.x;
  const int wid  = t >> 6;
  const int lane = t & 63;
  const int wm = wid & 1, wn = wid >> 1;
  const int quad = lane >> 4, l15 = lane & 15;

  int bx = blockIdx.x;
  { const int nwg = gridDim.x;
    if ((nwg & 7) == 0) { const int c = nwg >> 3; bx = (bx & 7)*c + (bx >> 3); } }
  const int mt = bx % p.MT;
  const int nt = bx / p.MT;

  const int swz = ((t & 3) ^ ((t >> 3) & 3)) * 16;
  const int8_t* Aa = p.A + ((long)mt*128 + (t >> 2))*K + swz;
  const int8_t* Bb = p.W + ((long)nt*128 + (t >> 2))*K + swz;

  auto issue = [&](int buf, int kt) {
    const long kOff = (long)kt * 64;
    GLDS16(Aa + kOff, lsMem + buf*8192 + t*16);
    GLDS16(Bb + kOff, lsMem + 24576 + buf*8192 + t*16);
  };
  const int sq = (quad ^ ((l15 >> 1) & 3)) * 16;

  const i32x4 zero = {0, 0, 0, 0};
  i32x4 acc[4][2];
  #pragma unroll
  for (int i = 0; i < 4; ++i)
    #pragma unroll
    for (int j = 0; j < 2; ++j) acc[i][j] = zero;

  issue(0, 0);
  issue(1, 1);
  __builtin_amdgcn_s_waitcnt(0xF72);
  BARRIER();

  int bufR = 0, bufW = 2;
  #pragma unroll 1
  for (int kt = 0; kt < KT; ++kt) {
    if (kt + 2 < KT) issue(bufW, kt + 2);
    i32x4 af[4], bf[2];
    #pragma unroll
    for (int i = 0; i < 4; ++i)
      af[i] = *(const i32x4*)(lsMem + (bufR*128 + wm*64 + i*16 + l15)*64 + sq);
    #pragma unroll
    for (int j = 0; j < 2; ++j)
      bf[j] = *(const i32x4*)(lsMem + 24576 + (bufR*128 + wn*32 + j*16 + l15)*64 + sq);
    __builtin_amdgcn_s_setprio(1);
    #pragma unroll
    for (int i = 0; i < 4; ++i)
      #pragma unroll
      for (int j = 0; j < 2; ++j)
        acc[i][j] = __builtin_amdgcn_mfma_i32_16x16x64_i8(af[i], bf[j], acc[i][j], 0, 0, 0);
    __builtin_amdgcn_s_setprio(0);
    if (kt + 2 < KT)      __builtin_amdgcn_s_waitcnt(0xF72);
    else if (kt + 1 < KT) WAITV0();
    if (kt + 1 < KT) BARRIER();
    bufR = (bufR == 2) ? 0 : bufR + 1;
    bufW = (bufW == 2) ? 0 : bufW + 1;
  }
  BARRIER();

  const float sW  = p.amax[p.amaxIdx] / 127.f + 1e-8f;
  const float sAB = p.actS[p.sInIdx] * sW;
  const int i0 = mt*128 + wm*64;
  const int j0 = nt*128 + wn*32;
  int8_t* scr = lsMem + wid * (32 * 80);

  const float sO = p.actS[p.sOutIdx];
  const float c1 = sAB / sO;
  #pragma unroll
  for (int ii = 0; ii < 4; ++ii) {
    const int i = i0 + ii*16 + quad*4;
    const float4 b4 = *(const float4*)(p.bias + i);
    float c2[4];
    #pragma unroll
    for (int r = 0; r < 4; ++r) c2[r] = ((const float*)&b4)[r] / sO;
    #pragma unroll
    for (int jj = 0; jj < 2; ++jj) {
      uint32_t pk = 0;
      #pragma unroll
      for (int r = 0; r < 4; ++r) {
        float q = rclipf(fmaf((float)acc[ii][jj][r], c1, c2[r]));
        pk |= ((uint32_t)(uint8_t)(int8_t)(int)q) << (8*r);
      }
      const int row = jj*16 + l15;
      *(uint32_t*)(scr + row*80 + ii*16 + quad*4) = pk;
    }
  }
  WAITLGKM0();
  #pragma unroll
  for (int e = 0; e < 2; ++e) {
    const int c = e*64 + lane;
    const int row = c >> 2, cc = c & 3;
    i32x4 v = *(const i32x4*)(scr + row*80 + cc*16);
    *(i32x4*)(p.out8 + (long)(j0 + row)*p.ldOut + i0 + cc*16) = v;
  }
}

// ---------------- host launch ----------------
extern "C" void kernel_launch(void* const* d_in, const int* in_sizes, int n_in,
                              void* d_out, int out_size, void* d_ws, size_t ws_size,
                              hipStream_t stream) {
  (void)in_sizes; (void)n_in; (void)out_size; (void)ws_size;
  const float* x    = (const float*)d_in[0];
  const float* n1a  = (const float*)d_in[1];
  const float* n1b  = (const float*)d_in[2];
  const float* attw = (const float*)d_in[3];
  const float* attb = (const float*)d_in[4];
  const float* g1   = (const float*)d_in[5];
  const float* n2a  = (const float*)d_in[6];
  const float* n2b  = (const float*)d_in[7];
  const float* w1vt = (const float*)d_in[8];
  const float* b1vt = (const float*)d_in[9];
  const float* w1u  = (const float*)d_in[10];
  const float* b1u  = (const float*)d_in[11];
  const float* w2vt = (const float*)d_in[12];
  const float* b2vt = (const float*)d_in[13];
  const float* w2u  = (const float*)d_in[14];
  const float* b2u  = (const float*)d_in[15];
  const float* g2   = (const float*)d_in[16];
  const float* actS = (const float*)d_in[17];
  float* out = (float*)d_out;
  char* ws = (char*)d_ws;

  float*  amax = (float*)(ws + OFF_AMAX);
  int8_t* LUTG = (int8_t*)(ws + OFF_LUT);
  float*  qvec = (float*)(ws + OFF_QVEC);
  int8_t* WQA  = (int8_t*)(ws + OFF_WQA);
  int8_t* W1VT = (int8_t*)(ws + OFF_W1VT);
  int8_t* W1U  = (int8_t*)(ws + OFF_W1U);
  int8_t* W2VT = (int8_t*)(ws + OFF_W2VT);
  int8_t* W2U  = (int8_t*)(ws + OFF_W2U);
  int8_t* X1Q  = (int8_t*)(ws + OFF_X1Q);
  int8_t* A4   = (int8_t*)(ws + OFF_A4);
  int8_t* A7   = (int8_t*)(ws + OFF_A7);
  int8_t* A0T  = (int8_t*)(ws + OFF_A0T);
  int8_t* A2   = (int8_t*)(ws + OFF_A2);
  int8_t* A6   = (int8_t*)(ws + OFF_A6);

  hipMemsetAsync(amax, 0, 64, stream);
  absmax_k<<<dim3(32, 9), 256, 0, stream>>>(n1a, attw, g1, n2a, w1vt, w1u, w2vt, w2u, g2, amax);
  prep_vec_k<<<1, 768, 0, stream>>>(n1a, n1b, g1, n2a, n2b, g2, amax, actS, qvec, LUTG);
  quant_all_k<<<dim3(1152, 5), 256, 0, stream>>>(w1vt, w1u, w2vt, w2u, attw, amax,
                                                 W1VT, W1U, W2VT, W2U, WQA);
  stageA_k<<<dim3(12, 4, 128), 256, 0, stream>>>(x, qvec, qvec + 768, A0T);

  // attn (verified): per-batch Out[d,m] = sum_n A0T[b][d][n] * WQA[m][n]
  GemmParams pa = {};
  pa.A = A0T; pa.W = WQA; pa.K = 256; pa.MT = 6; pa.NT = 2;
  pa.batchStrideA = (long)D_*256;
  pa.actS = actS; pa.amax = amax; pa.amaxIdx = 1; pa.sInIdx = 0;
  pa.bias = attb; pa.xorg = x;
  pa.g1s = qvec + 1536; pa.a2s8 = qvec + 2304; pa.b2s = qvec + 3072;
  pa.X1q = X1Q; pa.A2 = A2;
  gemm_i8<0><<<dim3(12, 128), 256, 0, stream>>>(pa);

  // fc1_VT (s1): A=W1VT [384][768], W=A2 -> A4. grid 588
  GemmParams p1 = {};
  p1.A = W1VT; p1.W = A2; p1.K = D_; p1.MT = R_/128; p1.NT = TOK/128;
  p1.actS = actS; p1.amax = amax; p1.amaxIdx = 4; p1.sInIdx = 2; p1.sOutIdx = 4;
  p1.bias = b1vt; p1.out8 = A4; p1.ldOut = R_;
  gemm_s1<1, 12><<<dim3((R_/128)*(TOK/128)), 512, 0, stream>>>(p1);

  // fc1_U (areg): W1U rows in VGPRs, A4 streamed via LDS. grid 6 x 392 = 2352
  GemmParams p2 = {};
  p2.A = W1U; p2.W = A4;
  p2.actS = actS; p2.amax = amax;
  p2.bias = b1u; p2.out8 = A6; p2.lutG = LUTG;
  fc1u_areg<<<dim3(6*(TOK/64)), 512, 0, stream>>>(p2);

  // fc2_VT (s1): A=W2VT [384][3072], W=A6 -> A7. grid 588
  GemmParams p3 = {};
  p3.A = W2VT; p3.W = A6; p3.K = H_; p3.MT = R_/128; p3.NT = TOK/128;
  p3.actS = actS; p3.amax = amax; p3.amaxIdx = 6; p3.sInIdx = 6; p3.sOutIdx = 7;
  p3.bias = b2vt; p3.out8 = A7; p3.ldOut = R_;
  gemm_s1<1, 48><<<dim3((R_/128)*(TOK/128)), 512, 0, stream>>>(p3);

  // fc2_U (wlds): W2U resident (256x384), stream A7 -> gamma2+res -> out fp32
  GemmParams p4 = {};
  p4.A = W2U; p4.W = A7; p4.K = R_; p4.MT = D_/256; p4.NT = TOK/128;
  p4.actS = actS; p4.amax = amax; p4.amaxIdx = 7; p4.sInIdx = 7;
  p4.bias = b2u; p4.g2s9 = qvec + 3840; p4.X1qIn = X1Q; p4.outF = out; p4.ldOut = D_;
  gemm_wlds<3, 4, 2, 4, 6, 1><<<dim3((D_/256)*(TOK/128)), 512, 0, stream>>>(p4);
}

// Round 7
// 490.274 us; speedup vs baseline: 1.1166x; 1.1166x over previous
//
#include <hip/hip_runtime.h>
#include <cstdint>
#include <cmath>

// Problem dims
#define B_   128
#define N_   196
#define D_   768
#define H_   3072
#define R_   384
#define TOK  (B_*N_)      // 25088

typedef int i32x4 __attribute__((ext_vector_type(4)));

// async global->LDS, 16B per lane; LDS dest = wave-uniform base + lane*16
#define GLDS16(g, l) __builtin_amdgcn_global_load_lds( \
    (const __attribute__((address_space(1))) void*)(g), \
    (__attribute__((address_space(3))) void*)(l), 16, 0, 0)

// s_waitcnt imm (gfx9): vmcnt[3:0], expcnt[6:4]=7, lgkmcnt[11:8]=15
#define WAITV4() __builtin_amdgcn_s_waitcnt(0xF74)   // vmcnt(4)
#define WAITV0() __builtin_amdgcn_s_waitcnt(0xF70)   // vmcnt(0)
#define WAITLGKM0() __asm__ volatile("s_waitcnt lgkmcnt(0)" ::: "memory")
#define BARRIER() do { __asm__ volatile("" ::: "memory"); \
                       __builtin_amdgcn_s_barrier(); \
                       __asm__ volatile("" ::: "memory"); } while (0)

// ---------------- workspace layout (bytes) ----------------
#define OFF_AMAX   0L
#define OFF_LUT    512L                  // 256-entry int8 GELU LUT
#define OFF_QVEC   1024L                 // 6 x 768 fp32 precomputed epilogue vectors
#define OFF_WQA    (32L*1024)            // attn weight int8 padded [256][256]
#define OFF_W1VT   (128L*1024)           // [384][768]
#define OFF_W1U    (512L*1024)           // [3072][384]
#define OFF_W2VT   (2L*1024*1024)        // [384][3072]
#define OFF_W2U    (3328L*1024)          // [768][384]
#define OFF_X1Q    (4L*1024*1024)        // int8 [25088][768]
#define OFF_A4     (24L*1024*1024)       // int8 [25088][384]
#define OFF_A7     (34L*1024*1024)       // int8 [25088][384]
#define OFF_A0T    (44L*1024*1024)       // int8 [128][768][256] (dead after attn)
#define OFF_A2     (68L*1024*1024)       // int8 [25088][768]    (dead after fc1_vt)
#define OFF_A6     (44L*1024*1024)       // int8 [25088][3072]   (overlays A0T+A2)

__device__ __forceinline__ float rclipf(float v) {
  // clip(round_half_even(v), -128, 127)
  return fminf(fmaxf(rintf(v), -128.f), 127.f);
}

// ---------------- absmax over 9 weight tensors ----------------
__global__ void absmax_k(const float* p0, const float* p1, const float* p2,
                         const float* p3, const float* p4, const float* p5,
                         const float* p6, const float* p7, const float* p8,
                         float* amax) {
  int tsel = blockIdx.y;
  const float* src; int n;
  switch (tsel) {
    case 0: src = p0; n = 768;     break;
    case 1: src = p1; n = N_*N_;   break;
    case 2: src = p2; n = 768;     break;
    case 3: src = p3; n = 768;     break;
    case 4: src = p4; n = R_*D_;   break;
    case 5: src = p5; n = H_*R_;   break;
    case 6: src = p6; n = R_*H_;   break;
    case 7: src = p7; n = D_*R_;   break;
    default: src = p8; n = 768;    break;
  }
  float m = 0.f;
  for (int i = blockIdx.x*blockDim.x + threadIdx.x; i < n; i += gridDim.x*blockDim.x)
    m = fmaxf(m, fabsf(src[i]));
  #pragma unroll
  for (int off = 32; off > 0; off >>= 1)
    m = fmaxf(m, __shfl_down(m, off));
  if ((threadIdx.x & 63) == 0)
    atomicMax((int*)(amax + tsel), __float_as_int(m));
}

// ---------------- precompute epilogue vectors + GELU LUT (1 block, 768 thr) ----------------
__global__ void prep_vec_k(const float* n1a, const float* n1b, const float* g1,
                           const float* n2a, const float* n2b, const float* g2,
                           const float* amax, const float* actS, float* dst,
                           int8_t* lut) {
  int i = threadIdx.x;  // 768
  float s0 = actS[0], s1 = actS[1], s2 = actS[2], s3 = actS[3];
  float s8 = actS[8], s9 = actS[9];
  float sw;
  sw = amax[0]/127.f + 1e-8f; float qn1a = sw * rclipf(n1a[i]/sw);
  dst[i]        = qn1a / s0;
  dst[768+i]    = n1b[i] / s0;
  sw = amax[2]/127.f + 1e-8f; float qg1 = sw * rclipf(g1[i]/sw);
  dst[1536+i]   = (s1 * qg1) / s8;
  sw = amax[3]/127.f + 1e-8f; float qn2a = sw * rclipf(n2a[i]/sw);
  dst[2304+i]   = (s8 * qn2a) / s2;
  dst[3072+i]   = n2b[i] / s2;
  sw = amax[8]/127.f + 1e-8f; float qg2 = sw * rclipf(g2[i]/sw);
  dst[3840+i]   = (s3 * qg2) / s9;
  if (i < 256) {
    float s5 = actS[5], s6 = actS[6];
    float v5 = s5 * (float)(i - 128);
    float g  = 0.5f * v5 * (1.f + erff(v5 * 0.70710678118654752f));
    lut[i] = (int8_t)(int)rclipf(g / s6);
  }
}

// ---------------- quantize all 5 matmul weights ----------------
__global__ void quant_all_k(const float* w1vt, const float* w1u, const float* w2vt,
                            const float* w2u, const float* attw, const float* amax,
                            int8_t* W1VT, int8_t* W1U, int8_t* W2VT, int8_t* W2U,
                            int8_t* WQA) {
  int sel = blockIdx.y;
  const float* src; int8_t* dst; int n; float am;
  switch (sel) {
    case 0: src = w1vt; dst = W1VT; n = R_*D_;  am = amax[4]; break;
    case 1: src = w1u;  dst = W1U;  n = H_*R_;  am = amax[5]; break;
    case 2: src = w2vt; dst = W2VT; n = R_*H_;  am = amax[6]; break;
    case 3: src = w2u;  dst = W2U;  n = D_*R_;  am = amax[7]; break;
    default: src = attw; dst = WQA; n = 65536;  am = amax[1]; break;
  }
  float s = am / 127.f + 1e-8f;
  if (sel < 4) {
    for (int i = blockIdx.x*blockDim.x + threadIdx.x; i < n; i += gridDim.x*blockDim.x)
      dst[i] = (int8_t)(int)rclipf(src[i] / s);
  } else {
    for (int i = blockIdx.x*blockDim.x + threadIdx.x; i < n; i += gridDim.x*blockDim.x) {
      int m = i >> 8, nn = i & 255;
      int8_t q = 0;
      if (m < N_ && nn < N_) q = (int8_t)(int)rclipf(attw[m*N_ + nn] / s);
      dst[i] = q;
    }
  }
}

// ---------------- stage A: norm1 affine + act-quant -> A0T[b][d][n256] ----------------
__global__ void stageA_k(const float* __restrict__ x, const float* __restrict__ n1as,
                         const float* __restrict__ n1bs, int8_t* __restrict__ A0T) {
  __shared__ int8_t ldsT[64*68];
  const int dt = blockIdx.x;
  const int nt = blockIdx.y;
  const int b  = blockIdx.z;
  const int d0 = dt*64, n0 = nt*64;
  const int tid = threadIdx.x;
  const int dc = tid & 63, nr4 = tid >> 6;
  const float qa = n1as[d0 + dc];
  const float bb = n1bs[d0 + dc];
  #pragma unroll 4
  for (int it = 0; it < 16; ++it) {
    int nl = nr4 + it*4;
    int n = n0 + nl;
    int8_t q = 0;
    if (n < N_) {
      float v = fmaf(x[((long)b*N_ + n)*D_ + d0 + dc], qa, bb);
      q = (int8_t)(int)rclipf(v);
    }
    ldsT[dc*68 + nl] = q;
  }
  __syncthreads();
  const int k = tid & 15, dr = tid >> 4;
  #pragma unroll
  for (int it = 0; it < 4; ++it) {
    int d = dr + it*16;
    uint32_t v = *(const uint32_t*)(&ldsT[d*68 + k*4]);
    *(uint32_t*)(&A0T[(long)b*(D_*256) + (long)(d0+d)*256 + n0 + k*4]) = v;
  }
}

// ---------------- generic i8 GEMM: r0 2-phase 128x128, 4 blocks/CU ----------------
// + T2 both-sides swizzle (r3/r5-verified): GLDS dest linear, global SOURCE
//   col-group pre-XOR'd with row bits 1-2, ds_read XORs the same on quad.
// + EPI1/EPI2: LDS-bounce epilogue (r3/r5-verified) -> 64B-contiguous dwordx4
//   stores; EPI2 uses bank-replicated lutR. EPI0/EPI3 epilogues = r0 verbatim.
struct GemmParams {
  const int8_t* A;
  const int8_t* W;
  int K, MT, NT;
  long batchStrideA;
  const float* actS;
  const float* amax;
  int amaxIdx, sInIdx, sOutIdx, sOut2Idx;
  const float* bias;     // indexed by i (EPI 1/2/3) or j (EPI 0)
  int8_t* out8;
  int ldOut;
  const float* xorg;     // EPI0
  const float* g1s;
  const float* a2s8;
  const float* b2s;
  int8_t* X1q;
  int8_t* A2;
  const float* g2s9;     // EPI3
  const int8_t* X1qIn;
  float* outF;
  const int8_t* lutG;    // EPI2
};

template<int EPI>
__launch_bounds__(256, 4)
__global__ void gemm_i8(GemmParams p) {
  __shared__ __align__(16) int8_t lsA[2][128][64];   // linear: global_load_lds dest
  __shared__ __align__(16) int8_t lsB[2][128][64];
  __shared__ uint32_t lutR[(EPI == 2) ? 64*32 : 4];  // bank-replicated GELU LUT
  const int K  = p.K;
  const int bx = blockIdx.x;
  const int mt = bx % p.MT;
  const int nt = bx / p.MT;
  const int t    = threadIdx.x;
  const int wid  = t >> 6;
  const int lane = t & 63;
  const int wm = wid & 1, wn = wid >> 1;
  const int quad = lane >> 4, l15 = lane & 15, l31 = lane & 31;

  if constexpr (EPI == 2) {
    // lane reads column (lane&31) -> bank == lane&31 -> conflict-free
    if (t < 64) {
      const uint8_t* lg = (const uint8_t*)p.lutG + t*4;
      uint32_t v = (uint32_t)lg[0] | ((uint32_t)lg[1] << 8) |
                   ((uint32_t)lg[2] << 16) | ((uint32_t)lg[3] << 24);
      #pragma unroll
      for (int c = 0; c < 32; ++c) lutR[t*32 + c] = v;
    }
    // visible after the K-loop's first barrier (writes land long before epilogue)
  }

  const int8_t* Abase = p.A + (long)blockIdx.y * p.batchStrideA + (long)mt*128*K;
  const int8_t* Wbase = p.W + (long)nt*128*K;

  // T2 staging-side: thread t covers LDS row t>>2, col-group t&3; its global
  // source col-group = (t&3) ^ ((t>>3)&3)  (row bits 1-2). Dest stays linear.
  const int swz = ((t & 3) ^ ((t >> 3) & 3)) * 16;
  const int8_t* Ab = Abase + (long)(t >> 2)*K + swz;
  const int8_t* Bb = Wbase + (long)(t >> 2)*K + swz;
  const long half = 64L * K;

  auto issue = [&](int kt) {
    const int buf = kt & 1;
    const long k = (long)kt << 6;
    GLDS16(Ab + k,        &lsA[buf][0][0]  + t*16);
    GLDS16(Ab + half + k, &lsA[buf][64][0] + t*16);
    GLDS16(Bb + k,        &lsB[buf][0][0]  + t*16);
    GLDS16(Bb + half + k, &lsB[buf][64][0] + t*16);
  };

  // T2 read-side XOR: row low bits come from l15
  const int sq = (quad ^ ((l15 >> 1) & 3)) * 16;

  const i32x4 zero = {0, 0, 0, 0};
  i32x4 acc[4][4];
  #pragma unroll
  for (int i = 0; i < 4; ++i)
    #pragma unroll
    for (int j = 0; j < 4; ++j) acc[i][j] = zero;

  const int KT = K >> 6;
  issue(0);
  for (int kt = 0; kt < KT; ++kt) {
    const int cur = kt & 1;
    if (kt + 1 < KT) { issue(kt + 1); WAITV4(); }   // tile kt resident; kt+1 in flight
    else             { WAITV0(); }
    BARRIER();
    i32x4 af[4], bf[4];
    #pragma unroll
    for (int i = 0; i < 4; ++i)
      af[i] = *(const i32x4*)(&lsA[cur][wm*64 + i*16 + l15][0] + sq);
    #pragma unroll
    for (int j = 0; j < 4; ++j)
      bf[j] = *(const i32x4*)(&lsB[cur][wn*64 + j*16 + l15][0] + sq);
    #pragma unroll
    for (int i = 0; i < 4; ++i)
      #pragma unroll
      for (int j = 0; j < 4; ++j)
        acc[i][j] = __builtin_amdgcn_mfma_i32_16x16x64_i8(af[i], bf[j], acc[i][j], 0, 0, 0);
    BARRIER();                                       // reads done before buf's next DMA
  }
  // After the final barrier all LDS reads are drained -> lsA/lsB reusable.

  // ---- epilogue ---- C/D layout (16x16): col=lane&15, row=quad*4+reg
  const float sW  = p.amax[p.amaxIdx] / 127.f + 1e-8f;
  const float sAB = p.actS[p.sInIdx] * sW;
  const int i0 = mt*128 + wm*64;
  const int j0 = nt*128 + wn*64;

  if constexpr (EPI == 1 || EPI == 2) {
    // quant (EPI1) or quant+GELU-LUT (EPI2) -> per-wave LDS bounce -> dwordx4
    int8_t* scr = ((wid < 2) ? (int8_t*)&lsA[0][0][0] : (int8_t*)&lsB[0][0][0])
                + (wid & 1)*(64*80);     // 64 rows x (64 + 16 pad)
    const float sO = p.actS[p.sOutIdx];
    const float c1 = sAB / sO;
    #pragma unroll
    for (int ii = 0; ii < 4; ++ii) {
      const int i = i0 + ii*16 + quad*4;
      const float4 b4 = *(const float4*)(p.bias + i);
      float c2[4];
      #pragma unroll
      for (int r = 0; r < 4; ++r) c2[r] = ((const float*)&b4)[r] / sO;
      #pragma unroll
      for (int jj = 0; jj < 4; ++jj) {
        uint32_t pk = 0;
        #pragma unroll
        for (int r = 0; r < 4; ++r) {
          if constexpr (EPI == 1) {
            float q = rclipf(fmaf((float)acc[ii][jj][r], c1, c2[r]));
            pk |= ((uint32_t)(uint8_t)(int8_t)(int)q) << (8*r);
          } else {
            int q5 = (int)rclipf(fmaf((float)acc[ii][jj][r], c1, c2[r])) + 128;
            uint32_t v = lutR[(q5 >> 2)*32 + l31];
            pk |= ((v >> ((q5 & 3)*8)) & 0xffu) << (8*r);
          }
        }
        const int row = jj*16 + l15;
        *(uint32_t*)(scr + row*80 + ii*16 + quad*4) = pk;
      }
    }
    WAITLGKM0();   // per-wave scratch: own writes drained, no barrier needed
    #pragma unroll
    for (int e = 0; e < 4; ++e) {          // 64 rows x 4 dwordx4-chunks
      const int c = e*64 + lane;
      const int row = c >> 2, cc = c & 3;
      i32x4 v = *(const i32x4*)(scr + row*80 + cc*16);
      *(i32x4*)(p.out8 + (long)(j0 + row)*p.ldOut + i0 + cc*16) = v;
    }
  } else {
    #pragma unroll
    for (int ii = 0; ii < 4; ++ii) {
      const int i = i0 + ii*16 + quad*4;
      if constexpr (EPI == 0) {
        // i = d (0..767), j = m patch (guard <196), batch = blockIdx.y
        const float c1     = sAB / p.actS[1];
        const float inv_s8 = 1.f / p.actS[8];
        const float4 g1s4 = *(const float4*)(p.g1s + i);
        const float4 a2s4 = *(const float4*)(p.a2s8 + i);
        const float4 b2s4 = *(const float4*)(p.b2s + i);
        #pragma unroll
        for (int jj = 0; jj < 4; ++jj) {
          const int j = j0 + jj*16 + l15;
          if (j < N_) {
            const float c2 = p.bias[j] / p.actS[1];
            const long tok = (long)blockIdx.y * N_ + j;
            const float4 xo = *(const float4*)(p.xorg + tok*D_ + i);
            uint32_t pk8 = 0, pk2 = 0;
            #pragma unroll
            for (int r = 0; r < 4; ++r) {
              float accf = (float)acc[ii][jj][r];
              float q1 = rclipf(fmaf(accf, c1, c2));
              float q8 = rclipf(fmaf(q1, ((const float*)&g1s4)[r],
                                     ((const float*)&xo)[r] * inv_s8));
              float q2 = rclipf(fmaf(q8, ((const float*)&a2s4)[r],
                                     ((const float*)&b2s4)[r]));
              pk8 |= ((uint32_t)(uint8_t)(int8_t)(int)q8) << (8*r);
              pk2 |= ((uint32_t)(uint8_t)(int8_t)(int)q2) << (8*r);
            }
            *(uint32_t*)(p.X1q + tok*D_ + i) = pk8;
            *(uint32_t*)(p.A2  + tok*D_ + i) = pk2;
          }
        }
      } else {  // EPI == 3: block act4 + gamma2 + residual(X1q) + add_2 -> fp32
        const float s3v = p.actS[3], s9v = p.actS[9];
        const float c1  = sAB / s3v;
        const float c89 = p.actS[8] / s9v;
        const float4 b4 = *(const float4*)(p.bias + i);
        const float4 g4 = *(const float4*)(p.g2s9 + i);
        float c2[4];
        #pragma unroll
        for (int r = 0; r < 4; ++r) c2[r] = ((const float*)&b4)[r] / s3v;
        #pragma unroll
        for (int jj = 0; jj < 4; ++jj) {
          const int j = j0 + jj*16 + l15;
          const uint32_t pk8 = *(const uint32_t*)(p.X1qIn + (long)j*D_ + i);
          float4 o;
          #pragma unroll
          for (int r = 0; r < 4; ++r) {
            float q3 = rclipf(fmaf((float)acc[ii][jj][r], c1, c2[r]));
            float q8 = (float)(int8_t)(uint8_t)(pk8 >> (8*r));
            float q9 = rclipf(fmaf(q3, ((const float*)&g4)[r], q8 * c89));
            ((float*)&o)[r] = s9v * q9;
          }
          *(float4*)(p.outF + (long)j*D_ + i) = o;
        }
      }
    }
  }
}

// ---------------- host launch ----------------
extern "C" void kernel_launch(void* const* d_in, const int* in_sizes, int n_in,
                              void* d_out, int out_size, void* d_ws, size_t ws_size,
                              hipStream_t stream) {
  (void)in_sizes; (void)n_in; (void)out_size; (void)ws_size;
  const float* x    = (const float*)d_in[0];
  const float* n1a  = (const float*)d_in[1];
  const float* n1b  = (const float*)d_in[2];
  const float* attw = (const float*)d_in[3];
  const float* attb = (const float*)d_in[4];
  const float* g1   = (const float*)d_in[5];
  const float* n2a  = (const float*)d_in[6];
  const float* n2b  = (const float*)d_in[7];
  const float* w1vt = (const float*)d_in[8];
  const float* b1vt = (const float*)d_in[9];
  const float* w1u  = (const float*)d_in[10];
  const float* b1u  = (const float*)d_in[11];
  const float* w2vt = (const float*)d_in[12];
  const float* b2vt = (const float*)d_in[13];
  const float* w2u  = (const float*)d_in[14];
  const float* b2u  = (const float*)d_in[15];
  const float* g2   = (const float*)d_in[16];
  const float* actS = (const float*)d_in[17];
  float* out = (float*)d_out;
  char* ws = (char*)d_ws;

  float*  amax = (float*)(ws + OFF_AMAX);
  int8_t* LUTG = (int8_t*)(ws + OFF_LUT);
  float*  qvec = (float*)(ws + OFF_QVEC);
  int8_t* WQA  = (int8_t*)(ws + OFF_WQA);
  int8_t* W1VT = (int8_t*)(ws + OFF_W1VT);
  int8_t* W1U  = (int8_t*)(ws + OFF_W1U);
  int8_t* W2VT = (int8_t*)(ws + OFF_W2VT);
  int8_t* W2U  = (int8_t*)(ws + OFF_W2U);
  int8_t* X1Q  = (int8_t*)(ws + OFF_X1Q);
  int8_t* A4   = (int8_t*)(ws + OFF_A4);
  int8_t* A7   = (int8_t*)(ws + OFF_A7);
  int8_t* A0T  = (int8_t*)(ws + OFF_A0T);
  int8_t* A2   = (int8_t*)(ws + OFF_A2);
  int8_t* A6   = (int8_t*)(ws + OFF_A6);

  hipMemsetAsync(amax, 0, 64, stream);
  absmax_k<<<dim3(32, 9), 256, 0, stream>>>(n1a, attw, g1, n2a, w1vt, w1u, w2vt, w2u, g2, amax);
  prep_vec_k<<<1, 768, 0, stream>>>(n1a, n1b, g1, n2a, n2b, g2, amax, actS, qvec, LUTG);
  quant_all_k<<<dim3(1152, 5), 256, 0, stream>>>(w1vt, w1u, w2vt, w2u, attw, amax,
                                                 W1VT, W1U, W2VT, W2U, WQA);
  stageA_k<<<dim3(12, 4, 128), 256, 0, stream>>>(x, qvec, qvec + 768, A0T);

  // attn: per-batch Out[d,m] = sum_n A0T[b][d][n] * WQA[m][n]; fused through act3
  GemmParams pa = {};
  pa.A = A0T; pa.W = WQA; pa.K = 256; pa.MT = 6; pa.NT = 2;
  pa.batchStrideA = (long)D_*256;
  pa.actS = actS; pa.amax = amax; pa.amaxIdx = 1; pa.sInIdx = 0;
  pa.bias = attb; pa.xorg = x;
  pa.g1s = qvec + 1536; pa.a2s8 = qvec + 2304; pa.b2s = qvec + 3072;
  pa.X1q = X1Q; pa.A2 = A2;
  gemm_i8<0><<<dim3(12, 128), 256, 0, stream>>>(pa);

  // fc1_VT: A=W1VT [384][768], W=A2 [25088][768] -> A4 [tok][384]
  GemmParams p1 = {};
  p1.A = W1VT; p1.W = A2; p1.K = D_; p1.MT = R_/128; p1.NT = TOK/128;
  p1.actS = actS; p1.amax = amax; p1.amaxIdx = 4; p1.sInIdx = 2; p1.sOutIdx = 4;
  p1.bias = b1vt; p1.out8 = A4; p1.ldOut = R_;
  gemm_i8<1><<<dim3((R_/128)*(TOK/128)), 256, 0, stream>>>(p1);

  // fc1_U: A=W1U [3072][384], W=A4 -> q5->GELU(LUT)->q6 -> A6 [tok][3072]
  GemmParams p2 = {};
  p2.A = W1U; p2.W = A4; p2.K = R_; p2.MT = H_/128; p2.NT = TOK/128;
  p2.actS = actS; p2.amax = amax; p2.amaxIdx = 5; p2.sInIdx = 4; p2.sOutIdx = 5; p2.sOut2Idx = 6;
  p2.bias = b1u; p2.out8 = A6; p2.ldOut = H_; p2.lutG = LUTG;
  gemm_i8<2><<<dim3((H_/128)*(TOK/128)), 256, 0, stream>>>(p2);

  // fc2_VT: A=W2VT [384][3072], W=A6 -> A7 [tok][384]
  GemmParams p3 = {};
  p3.A = W2VT; p3.W = A6; p3.K = H_; p3.MT = R_/128; p3.NT = TOK/128;
  p3.actS = actS; p3.amax = amax; p3.amaxIdx = 6; p3.sInIdx = 6; p3.sOutIdx = 7;
  p3.bias = b2vt; p3.out8 = A7; p3.ldOut = R_;
  gemm_i8<1><<<dim3((R_/128)*(TOK/128)), 256, 0, stream>>>(p3);

  // fc2_U: A=W2U [768][384], W=A7 -> q3->gamma2->+x1->q9 -> out fp32
  GemmParams p4 = {};
  p4.A = W2U; p4.W = A7; p4.K = R_; p4.MT = D_/128; p4.NT = TOK/128;
  p4.actS = actS; p4.amax = amax; p4.amaxIdx = 7; p4.sInIdx = 7;
  p4.bias = b2u; p4.g2s9 = qvec + 3840; p4.X1qIn = X1Q; p4.outF = out; p4.ldOut = D_;
  gemm_i8<3><<<dim3((D_/128)*(TOK/128)), 256, 0, stream>>>(p4);
}